// Round 16
// baseline (92.248 us; speedup 1.0000x reference)
//
#include <hip/hip_runtime.h>

typedef float f32x2 __attribute__((ext_vector_type(2)));
typedef float f32x16 __attribute__((ext_vector_type(16)));
typedef __bf16 bf16x8 __attribute__((ext_vector_type(8)));

static __device__ __forceinline__ unsigned short f2bf(float v) {
    unsigned u = __builtin_bit_cast(unsigned, v);
    unsigned r = (u + 0x7FFFu + ((u >> 16) & 1u)) >> 16;
    return (unsigned short)r;
}
static __device__ __forceinline__ bf16x8 ldg8(const unsigned short* p) {
    uint4 u = *(const uint4*)p;
    return __builtin_bit_cast(bf16x8, u);
}
static __device__ __forceinline__ f32x16 mfma32(bf16x8 a, bf16x8 b, f32x16 c) {
    return __builtin_amdgcn_mfma_f32_32x32x16_bf16(a, b, c, 0, 0, 0);
}

// x + x[lane^32] on the VALU pipe (permlane32_swap), not the LDS pipe.
static __device__ __forceinline__ float sum_xor32(float x) {
#if __has_builtin(__builtin_amdgcn_permlane32_swap)
    unsigned u = __builtin_bit_cast(unsigned, x);
    auto r = __builtin_amdgcn_permlane32_swap(u, u, false, false);
    return __builtin_bit_cast(float, (unsigned)r[0]) +
           __builtin_bit_cast(float, (unsigned)r[1]);
#else
    return x + __shfl_xor(x, 32);
#endif
}

// ---------------------------------------------------------------------------
// prep_M: simulate the 64 basis states for each f -> M_f (64x64 complex),
// bf16, layout [f][re/im][d][k]. (verified R1-R15)
// ---------------------------------------------------------------------------
__global__ __launch_bounds__(256) void prep_M(const float* __restrict__ wts,
                                              unsigned short* __restrict__ Mhi) {
    __shared__ float gls[12][8];
    const int f = blockIdx.x >> 4;
    const int tid = threadIdx.x;
    if (tid < 12) {
        int l = tid / 6, w = tid % 6;
        const float* p = wts + ((f * 2 + l) * 6 + w) * 3;
        float phi = p[0], theta = p[1], omega = p[2];
        float c, s; sincosf(0.5f * theta, &s, &c);
        float sapo, capo, samo, camo;
        sincosf(0.5f * (phi + omega), &sapo, &capo);
        sincosf(0.5f * (phi - omega), &samo, &camo);
        float* o = gls[tid];
        o[0] =  capo * c;  o[1] = -sapo * c;
        o[2] = -camo * s;  o[3] = -samo * s;
        o[4] =  camo * s;  o[5] = -samo * s;
        o[6] =  capo * c;  o[7] =  sapo * c;
    }
    __syncthreads();

    const int lane = tid & 63;
    const int wid  = tid >> 6;
    const int bas  = (blockIdx.x & 15) * 4 + wid;

    int src0 = lane, src1 = lane;
#pragma unroll
    for (int w = 5; w >= 0; --w) { int tq = (w + 1) % 6; src0 ^= ((src0 >> (5 - w)) & 1) << (5 - tq); }
#pragma unroll
    for (int w = 5; w >= 0; --w) { int tq = (w + 2) % 6; src1 ^= ((src1 >> (5 - w)) & 1) << (5 - tq); }

    float ar = (lane == bas) ? 1.0f : 0.0f, ai = 0.0f;
#pragma unroll
    for (int rep = 0; rep < 2; ++rep) {
#pragma unroll
        for (int l = 0; l < 2; ++l) {
#pragma unroll
            for (int w = 0; w < 6; ++w) {
                const float* gp = gls[l * 6 + w];
                const float4 uA = *(const float4*)gp;
                const float4 uB = *(const float4*)(gp + 4);
                const int m = 32 >> w;
                const float br = __shfl_xor(ar, m);
                const float bi = __shfl_xor(ai, m);
                const bool hi = (lane & m) != 0;
                const float cmr = hi ? uB.z : uA.x;
                const float cmi = hi ? uB.w : uA.y;
                const float cpr = hi ? uB.x : uA.z;
                const float cpi = hi ? uB.y : uA.w;
                const float nr = cmr * ar - cmi * ai + cpr * br - cpi * bi;
                const float ni = cmr * ai + cmi * ar + cpr * bi + cpi * br;
                ar = nr; ai = ni;
            }
            const int src = l ? src1 : src0;
            ar = __shfl(ar, src);
            ai = __shfl(ai, src);
        }
    }
    Mhi[((f * 2 + 0) * 64 + lane) * 64 + bas] = f2bf(ar);
    Mhi[((f * 2 + 1) * 64 + lane) * 64 + bas] = f2bf(ai);
}

// ---------------------------------------------------------------------------
// Main: 961 blocks x 512 threads. 8 waves = (d-quarter dq = w&3) x (tile
// t = w>>2). Per-wave work halved vs R15; waves/CU 15 -> 30. Same verified
// math: psi swizzle, A-row mapping, d-bit sign algebra, packed zbuf.
// ---------------------------------------------------------------------------
__global__ __launch_bounds__(512, 8) void qconv_main(
        const float* __restrict__ x,
        const unsigned short* __restrict__ Mhi,
        float* __restrict__ out) {
    __shared__ __align__(16) unsigned short psiH[2][4096];   // 16 KB
    __shared__ float zbuf[2][4][64][8];                      // 16 KB [t][dq][p][q8]

    const int tid  = threadIdx.x;
    const int lane = tid & 63;
    const int w8   = tid >> 6;      // 0..7
    const int dq   = w8 & 3;        // d-quarter of this wave
    const int tw   = w8 >> 2;       // tile of this wave
    const int bid  = blockIdx.x;

    // ---- front-end: thread handles (t = tid>>8, p, q) — one tile each ----
    {
        const int t = tid >> 8;
        const int p = (tid >> 2) & 63;   // patch 0..63
        const int q = tid & 3;           // channel / k-chunk
        const int n = bid * 64 + p;
        const int b0 = n / 961, pos = n - b0 * 961;
        const int i = pos / 31, j = pos - i * 31;
        const float* base = x + ((((b0 + t * 64) * 4 + q) * 64) + i * 2) * 64 + j * 2;
        float v[16];
#pragma unroll
        for (int kh = 0; kh < 4; ++kh) {
            const float* r = base + kh * 64;
            *(f32x2*)&v[kh * 4]     = *(const f32x2*)r;
            *(f32x2*)&v[kh * 4 + 2] = *(const f32x2*)(r + 2);
        }
        float ss = 0.f;
#pragma unroll
        for (int k = 0; k < 16; ++k) ss += v[k] * v[k];
        ss += __shfl_xor(ss, 1);
        ss += __shfl_xor(ss, 2);
        const float rn = rsqrtf(ss);
        unsigned hu[8];
#pragma unroll
        for (int k2 = 0; k2 < 8; ++k2) {
            __bf16 h0 = (__bf16)(v[2 * k2] * rn);
            __bf16 h1 = (__bf16)(v[2 * k2 + 1] * rn);
            hu[k2] = (unsigned)__builtin_bit_cast(unsigned short, h0)
                   | ((unsigned)__builtin_bit_cast(unsigned short, h1) << 16);
        }
        const int s0i = p * 64 + ((2 * q) ^ (p & 7)) * 8;
        const int s1i = p * 64 + ((2 * q + 1) ^ (p & 7)) * 8;
        *(uint4*)&psiH[t][s0i] = make_uint4(hu[0], hu[1], hu[2], hu[3]);
        *(uint4*)&psiH[t][s1i] = make_uint4(hu[4], hu[5], hu[6], hu[7]);
    }

    // A-row base (verified mapping): reim lane bit4, d = dq*16+(lane&15), k-half hi5*8
    const int hi5  = lane >> 5;
    const int arow = ((lane >> 4) & 1) * 4096 + (dq * 16 + (lane & 15)) * 64 + hi5 * 8;

    // prefetch A for f=0 — hides under the barrier
    bf16x8 A[4];
#pragma unroll
    for (int ks = 0; ks < 4; ++ks) A[ks] = ldg8(Mhi + arow + ks * 16);

    __syncthreads();

    // ---- B-fragments for this wave's tile ----
    bf16x8 Bh[2][4];
    const int pc = lane & 31;
#pragma unroll
    for (int ct = 0; ct < 2; ++ct) {
        const int pp = ct * 32 + pc;
#pragma unroll
        for (int ks = 0; ks < 4; ++ks) {
            const int idx = pp * 64 + ((2 * ks + hi5) ^ (pp & 7)) * 8;
            Bh[ct][ks] = __builtin_bit_cast(bf16x8, *(const uint4*)&psiH[tw][idx]);
        }
    }

    // hoisted combine addressing (f-independent): u covers (t, q, p)
    const int cnn  = bid * 64 + (tid & 63);   // recomputed per combine index below
    (void)cnn;

#pragma unroll 1
    for (int f = 0; f < 4; ++f) {
        f32x16 C0, C1;
#pragma unroll
        for (int r = 0; r < 16; ++r) { C0[r] = 0.f; C1[r] = 0.f; }
#pragma unroll
        for (int ks = 0; ks < 4; ++ks) {
            C0 = mfma32(A[ks], Bh[0][ks], C0);
            C1 = mfma32(A[ks], Bh[1][ks], C1);
        }

        // prefetch next f's A
        bf16x8 An[4];
        if (f < 3) {
#pragma unroll
            for (int ks = 0; ks < 4; ++ks)
                An[ks] = ldg8(Mhi + (f + 1) * 8192 + arow + ks * 16);
        }

#pragma unroll
        for (int ct = 0; ct < 2; ++ct) {
            const f32x16 Cv = ct ? C1 : C0;
            float P[8];
#pragma unroll
            for (int r = 0; r < 8; ++r) P[r] = Cv[r] * Cv[r] + Cv[r + 8] * Cv[r + 8];
            const float e0 = P[0] + P[1], o0 = P[0] - P[1];
            const float e1 = P[2] + P[3], o1 = P[2] - P[3];
            const float e2 = P[4] + P[5], o2 = P[4] - P[5];
            const float e3 = P[6] + P[7], o3 = P[6] - P[7];
            const float s01 = e0 + e1, s23 = e2 + e3;
            const float S = s01 + s23;
            const float Sr  = sum_xor32(S);
            const float Z2r = sum_xor32(s01 - s23);               // d bit3
            const float Z3r = sum_xor32(hi5 ? -S : S);            // d bit2
            const float Z4r = sum_xor32((e0 - e1) + (e2 - e3));   // d bit1
            const float Z5r = sum_xor32(o0 + o1 + o2 + o3);       // d bit0
            const int pp = ct * 32 + pc;
            float* zb = &zbuf[tw][dq][pp][0];
            f32x2 d2;
            float d1;
            if (hi5 == 0) {
                d2[0] = (dq & 2) ? -Sr : Sr;   // q0: d bit5 = dq>>1
                d2[1] = (dq & 1) ? -Sr : Sr;   // q1: d bit4 = dq&1
                d1 = Z2r;
            } else {
                d2[0] = Z3r;
                d2[1] = Z4r;
                d1 = Z5r;
            }
            *(f32x2*)(zb + hi5 * 4) = d2;
            zb[hi5 * 4 + 2] = d1;
        }
        __syncthreads();

        // ---- combine across d-quarters + store: u covers (t, q, p) ----
#pragma unroll 1
        for (int u = tid; u < 768; u += 512) {
            const int t   = u / 384;
            const int rem = u - t * 384;
            const int q   = rem >> 6;
            const int p   = rem & 63;
            const int slot = q + (q >= 3);     // packed layout: 0,1,2,_,3,4,5
            const float* zb = &zbuf[t][0][p][slot];
            const float sum = zb[0] + zb[512] + zb[1024] + zb[1536];  // dq stride 64*8
            const int nn = bid * 64 + p;
            const int bb = nn / 961;
            const int pos = nn - bb * 961;
            out[((bb + t * 64) * 24 + f * 6 + q) * 961 + pos] = sum;
        }

        if (f < 3) {
            __syncthreads();   // zbuf reuse fence before next f's writes
#pragma unroll
            for (int ks = 0; ks < 4; ++ks) A[ks] = An[ks];
        }
    }
}

extern "C" void kernel_launch(void* const* d_in, const int* in_sizes, int n_in,
                              void* d_out, int out_size, void* d_ws, size_t ws_size,
                              hipStream_t stream) {
    const float* x   = (const float*)d_in[0];   // (128, 4, 64, 64)
    const float* wts = (const float*)d_in[1];   // (4, 2, 6, 3)
    float* out = (float*)d_out;                 // (128, 24, 31, 31)

    unsigned short* Mhi = (unsigned short*)d_ws;

    prep_M<<<64, 256, 0, stream>>>(wts, Mhi);

    // 123008 patches = 961 blocks x 2 tiles x 64 patches, 512 threads/block
    qconv_main<<<961, 512, 0, stream>>>(x, Mhi, out);
}

// Round 17
// 35.272 us; speedup vs baseline: 2.6153x; 2.6153x over previous
//
#include <hip/hip_runtime.h>

typedef float f32x2 __attribute__((ext_vector_type(2)));
typedef float f32x16 __attribute__((ext_vector_type(16)));
typedef __bf16 bf16x8 __attribute__((ext_vector_type(8)));

static __device__ __forceinline__ unsigned short f2bf(float v) {
    unsigned u = __builtin_bit_cast(unsigned, v);
    unsigned r = (u + 0x7FFFu + ((u >> 16) & 1u)) >> 16;
    return (unsigned short)r;
}
static __device__ __forceinline__ bf16x8 ldg8(const unsigned short* p) {
    uint4 u = *(const uint4*)p;
    return __builtin_bit_cast(bf16x8, u);
}
static __device__ __forceinline__ f32x16 mfma32(bf16x8 a, bf16x8 b, f32x16 c) {
    return __builtin_amdgcn_mfma_f32_32x32x16_bf16(a, b, c, 0, 0, 0);
}

// x + x[lane^32] on the VALU pipe (permlane32_swap), not the LDS pipe.
static __device__ __forceinline__ float sum_xor32(float x) {
#if __has_builtin(__builtin_amdgcn_permlane32_swap)
    unsigned u = __builtin_bit_cast(unsigned, x);
    auto r = __builtin_amdgcn_permlane32_swap(u, u, false, false);
    return __builtin_bit_cast(float, (unsigned)r[0]) +
           __builtin_bit_cast(float, (unsigned)r[1]);
#else
    return x + __shfl_xor(x, 32);
#endif
}

// ---------------------------------------------------------------------------
// prep_M: simulate the 64 basis states for each f -> M_f (64x64 complex),
// bf16, layout [f][re/im][d][k]. (verified R1-R16)
// ---------------------------------------------------------------------------
__global__ __launch_bounds__(256) void prep_M(const float* __restrict__ wts,
                                              unsigned short* __restrict__ Mhi) {
    __shared__ float gls[12][8];
    const int f = blockIdx.x >> 4;
    const int tid = threadIdx.x;
    if (tid < 12) {
        int l = tid / 6, w = tid % 6;
        const float* p = wts + ((f * 2 + l) * 6 + w) * 3;
        float phi = p[0], theta = p[1], omega = p[2];
        float c, s; sincosf(0.5f * theta, &s, &c);
        float sapo, capo, samo, camo;
        sincosf(0.5f * (phi + omega), &sapo, &capo);
        sincosf(0.5f * (phi - omega), &samo, &camo);
        float* o = gls[tid];
        o[0] =  capo * c;  o[1] = -sapo * c;
        o[2] = -camo * s;  o[3] = -samo * s;
        o[4] =  camo * s;  o[5] = -samo * s;
        o[6] =  capo * c;  o[7] =  sapo * c;
    }
    __syncthreads();

    const int lane = tid & 63;
    const int wid  = tid >> 6;
    const int bas  = (blockIdx.x & 15) * 4 + wid;

    int src0 = lane, src1 = lane;
#pragma unroll
    for (int w = 5; w >= 0; --w) { int tq = (w + 1) % 6; src0 ^= ((src0 >> (5 - w)) & 1) << (5 - tq); }
#pragma unroll
    for (int w = 5; w >= 0; --w) { int tq = (w + 2) % 6; src1 ^= ((src1 >> (5 - w)) & 1) << (5 - tq); }

    float ar = (lane == bas) ? 1.0f : 0.0f, ai = 0.0f;
#pragma unroll
    for (int rep = 0; rep < 2; ++rep) {
#pragma unroll
        for (int l = 0; l < 2; ++l) {
#pragma unroll
            for (int w = 0; w < 6; ++w) {
                const float* gp = gls[l * 6 + w];
                const float4 uA = *(const float4*)gp;
                const float4 uB = *(const float4*)(gp + 4);
                const int m = 32 >> w;
                const float br = __shfl_xor(ar, m);
                const float bi = __shfl_xor(ai, m);
                const bool hi = (lane & m) != 0;
                const float cmr = hi ? uB.z : uA.x;
                const float cmi = hi ? uB.w : uA.y;
                const float cpr = hi ? uB.x : uA.z;
                const float cpi = hi ? uB.y : uA.w;
                const float nr = cmr * ar - cmi * ai + cpr * br - cpi * bi;
                const float ni = cmr * ai + cmi * ar + cpr * bi + cpi * br;
                ar = nr; ai = ni;
            }
            const int src = l ? src1 : src0;
            ar = __shfl(ar, src);
            ai = __shfl(ai, src);
        }
    }
    Mhi[((f * 2 + 0) * 64 + lane) * 64 + bas] = f2bf(ar);
    Mhi[((f * 2 + 1) * 64 + lane) * 64 + bas] = f2bf(ai);
}

// ---------------------------------------------------------------------------
// Main: 961 blocks x 512 threads. 8 waves = (d-quarter dq = w&3) x (tile
// t = w>>2). Per-wave work halved vs R15; 30 waves/CU offered.
// R16 structure with a sane VGPR cap: (512,4) -> 128 regs, no spill.
// ---------------------------------------------------------------------------
__global__ __launch_bounds__(512, 4) void qconv_main(
        const float* __restrict__ x,
        const unsigned short* __restrict__ Mhi,
        float* __restrict__ out) {
    __shared__ __align__(16) unsigned short psiH[2][4096];   // 16 KB
    __shared__ float zbuf[2][4][64][8];                      // 16 KB [t][dq][p][q8]

    const int tid  = threadIdx.x;
    const int lane = tid & 63;
    const int w8   = tid >> 6;      // 0..7
    const int dq   = w8 & 3;        // d-quarter of this wave
    const int tw   = w8 >> 2;       // tile of this wave
    const int bid  = blockIdx.x;

    // ---- front-end: thread handles (t = tid>>8, p, q) — one tile each ----
    {
        const int t = tid >> 8;
        const int p = (tid >> 2) & 63;   // patch 0..63
        const int q = tid & 3;           // channel / k-chunk
        const int n = bid * 64 + p;
        const int b0 = n / 961, pos = n - b0 * 961;
        const int i = pos / 31, j = pos - i * 31;
        const float* base = x + ((((b0 + t * 64) * 4 + q) * 64) + i * 2) * 64 + j * 2;
        float v[16];
#pragma unroll
        for (int kh = 0; kh < 4; ++kh) {
            const float* r = base + kh * 64;
            *(f32x2*)&v[kh * 4]     = *(const f32x2*)r;
            *(f32x2*)&v[kh * 4 + 2] = *(const f32x2*)(r + 2);
        }
        float ss = 0.f;
#pragma unroll
        for (int k = 0; k < 16; ++k) ss += v[k] * v[k];
        ss += __shfl_xor(ss, 1);
        ss += __shfl_xor(ss, 2);
        const float rn = rsqrtf(ss);
        unsigned hu[8];
#pragma unroll
        for (int k2 = 0; k2 < 8; ++k2) {
            __bf16 h0 = (__bf16)(v[2 * k2] * rn);
            __bf16 h1 = (__bf16)(v[2 * k2 + 1] * rn);
            hu[k2] = (unsigned)__builtin_bit_cast(unsigned short, h0)
                   | ((unsigned)__builtin_bit_cast(unsigned short, h1) << 16);
        }
        const int s0i = p * 64 + ((2 * q) ^ (p & 7)) * 8;
        const int s1i = p * 64 + ((2 * q + 1) ^ (p & 7)) * 8;
        *(uint4*)&psiH[t][s0i] = make_uint4(hu[0], hu[1], hu[2], hu[3]);
        *(uint4*)&psiH[t][s1i] = make_uint4(hu[4], hu[5], hu[6], hu[7]);
    }

    // A-row base (verified mapping): reim lane bit4, d = dq*16+(lane&15), k-half hi5*8
    const int hi5  = lane >> 5;
    const int arow = ((lane >> 4) & 1) * 4096 + (dq * 16 + (lane & 15)) * 64 + hi5 * 8;

    // prefetch A for f=0 — hides under the barrier
    bf16x8 A[4];
#pragma unroll
    for (int ks = 0; ks < 4; ++ks) A[ks] = ldg8(Mhi + arow + ks * 16);

    __syncthreads();

    // ---- B-fragments for this wave's tile ----
    bf16x8 Bh[2][4];
    const int pc = lane & 31;
#pragma unroll
    for (int ct = 0; ct < 2; ++ct) {
        const int pp = ct * 32 + pc;
#pragma unroll
        for (int ks = 0; ks < 4; ++ks) {
            const int idx = pp * 64 + ((2 * ks + hi5) ^ (pp & 7)) * 8;
            Bh[ct][ks] = __builtin_bit_cast(bf16x8, *(const uint4*)&psiH[tw][idx]);
        }
    }

#pragma unroll 1
    for (int f = 0; f < 4; ++f) {
        f32x16 C0, C1;
#pragma unroll
        for (int r = 0; r < 16; ++r) { C0[r] = 0.f; C1[r] = 0.f; }
#pragma unroll
        for (int ks = 0; ks < 4; ++ks) {
            C0 = mfma32(A[ks], Bh[0][ks], C0);
            C1 = mfma32(A[ks], Bh[1][ks], C1);
        }

        // prefetch next f's A
        bf16x8 An[4];
        if (f < 3) {
#pragma unroll
            for (int ks = 0; ks < 4; ++ks)
                An[ks] = ldg8(Mhi + (f + 1) * 8192 + arow + ks * 16);
        }

#pragma unroll
        for (int ct = 0; ct < 2; ++ct) {
            const f32x16 Cv = ct ? C1 : C0;
            float P[8];
#pragma unroll
            for (int r = 0; r < 8; ++r) P[r] = Cv[r] * Cv[r] + Cv[r + 8] * Cv[r + 8];
            const float e0 = P[0] + P[1], o0 = P[0] - P[1];
            const float e1 = P[2] + P[3], o1 = P[2] - P[3];
            const float e2 = P[4] + P[5], o2 = P[4] - P[5];
            const float e3 = P[6] + P[7], o3 = P[6] - P[7];
            const float s01 = e0 + e1, s23 = e2 + e3;
            const float S = s01 + s23;
            const float Sr  = sum_xor32(S);
            const float Z2r = sum_xor32(s01 - s23);               // d bit3
            const float Z3r = sum_xor32(hi5 ? -S : S);            // d bit2
            const float Z4r = sum_xor32((e0 - e1) + (e2 - e3));   // d bit1
            const float Z5r = sum_xor32(o0 + o1 + o2 + o3);       // d bit0
            const int pp = ct * 32 + pc;
            float* zb = &zbuf[tw][dq][pp][0];
            f32x2 d2;
            float d1;
            if (hi5 == 0) {
                d2[0] = (dq & 2) ? -Sr : Sr;   // q0: d bit5 = dq>>1
                d2[1] = (dq & 1) ? -Sr : Sr;   // q1: d bit4 = dq&1
                d1 = Z2r;
            } else {
                d2[0] = Z3r;
                d2[1] = Z4r;
                d1 = Z5r;
            }
            *(f32x2*)(zb + hi5 * 4) = d2;
            zb[hi5 * 4 + 2] = d1;
        }
        __syncthreads();

        // ---- combine across d-quarters + store: u covers (t, q, p) ----
#pragma unroll 1
        for (int u = tid; u < 768; u += 512) {
            const int t   = u / 384;
            const int rem = u - t * 384;
            const int q   = rem >> 6;
            const int p   = rem & 63;
            const int slot = q + (q >= 3);     // packed layout: 0,1,2,_,3,4,5
            const float* zb = &zbuf[t][0][p][slot];
            const float sum = zb[0] + zb[512] + zb[1024] + zb[1536];  // dq stride 64*8
            const int nn = bid * 64 + p;
            const int bb = nn / 961;
            const int pos = nn - bb * 961;
            out[((bb + t * 64) * 24 + f * 6 + q) * 961 + pos] = sum;
        }

        if (f < 3) {
            __syncthreads();   // zbuf reuse fence before next f's writes
#pragma unroll
            for (int ks = 0; ks < 4; ++ks) A[ks] = An[ks];
        }
    }
}

extern "C" void kernel_launch(void* const* d_in, const int* in_sizes, int n_in,
                              void* d_out, int out_size, void* d_ws, size_t ws_size,
                              hipStream_t stream) {
    const float* x   = (const float*)d_in[0];   // (128, 4, 64, 64)
    const float* wts = (const float*)d_in[1];   // (4, 2, 6, 3)
    float* out = (float*)d_out;                 // (128, 24, 31, 31)

    unsigned short* Mhi = (unsigned short*)d_ws;

    prep_M<<<64, 256, 0, stream>>>(wts, Mhi);

    // 123008 patches = 961 blocks x 2 tiles x 64 patches, 512 threads/block
    qconv_main<<<961, 512, 0, stream>>>(x, Mhi, out);
}

// Round 18
// 27.544 us; speedup vs baseline: 3.3491x; 1.2806x over previous
//
#include <hip/hip_runtime.h>

typedef float f32x2 __attribute__((ext_vector_type(2)));
typedef float f32x16 __attribute__((ext_vector_type(16)));
typedef __bf16 bf16x8 __attribute__((ext_vector_type(8)));

static __device__ __forceinline__ unsigned short f2bf(float v) {
    unsigned u = __builtin_bit_cast(unsigned, v);
    unsigned r = (u + 0x7FFFu + ((u >> 16) & 1u)) >> 16;
    return (unsigned short)r;
}
static __device__ __forceinline__ bf16x8 ldg8(const unsigned short* p) {
    uint4 u = *(const uint4*)p;
    return __builtin_bit_cast(bf16x8, u);
}
static __device__ __forceinline__ f32x16 mfma32(bf16x8 a, bf16x8 b, f32x16 c) {
    return __builtin_amdgcn_mfma_f32_32x32x16_bf16(a, b, c, 0, 0, 0);
}

// x + x[lane^32] on the VALU pipe (permlane32_swap), not the LDS pipe.
static __device__ __forceinline__ float sum_xor32(float x) {
#if __has_builtin(__builtin_amdgcn_permlane32_swap)
    unsigned u = __builtin_bit_cast(unsigned, x);
    auto r = __builtin_amdgcn_permlane32_swap(u, u, false, false);
    return __builtin_bit_cast(float, (unsigned)r[0]) +
           __builtin_bit_cast(float, (unsigned)r[1]);
#else
    return x + __shfl_xor(x, 32);
#endif
}

// ---------------------------------------------------------------------------
// prep_M: simulate the 64 basis states for each f -> M_f (64x64 complex),
// bf16, layout [f][re/im][d][k]. (verified R1-R17)
// ---------------------------------------------------------------------------
__global__ __launch_bounds__(256) void prep_M(const float* __restrict__ wts,
                                              unsigned short* __restrict__ Mhi) {
    __shared__ float gls[12][8];
    const int f = blockIdx.x >> 4;
    const int tid = threadIdx.x;
    if (tid < 12) {
        int l = tid / 6, w = tid % 6;
        const float* p = wts + ((f * 2 + l) * 6 + w) * 3;
        float phi = p[0], theta = p[1], omega = p[2];
        float c, s; sincosf(0.5f * theta, &s, &c);
        float sapo, capo, samo, camo;
        sincosf(0.5f * (phi + omega), &sapo, &capo);
        sincosf(0.5f * (phi - omega), &samo, &camo);
        float* o = gls[tid];
        o[0] =  capo * c;  o[1] = -sapo * c;
        o[2] = -camo * s;  o[3] = -samo * s;
        o[4] =  camo * s;  o[5] = -samo * s;
        o[6] =  capo * c;  o[7] =  sapo * c;
    }
    __syncthreads();

    const int lane = tid & 63;
    const int wid  = tid >> 6;
    const int bas  = (blockIdx.x & 15) * 4 + wid;

    int src0 = lane, src1 = lane;
#pragma unroll
    for (int w = 5; w >= 0; --w) { int tq = (w + 1) % 6; src0 ^= ((src0 >> (5 - w)) & 1) << (5 - tq); }
#pragma unroll
    for (int w = 5; w >= 0; --w) { int tq = (w + 2) % 6; src1 ^= ((src1 >> (5 - w)) & 1) << (5 - tq); }

    float ar = (lane == bas) ? 1.0f : 0.0f, ai = 0.0f;
#pragma unroll
    for (int rep = 0; rep < 2; ++rep) {
#pragma unroll
        for (int l = 0; l < 2; ++l) {
#pragma unroll
            for (int w = 0; w < 6; ++w) {
                const float* gp = gls[l * 6 + w];
                const float4 uA = *(const float4*)gp;
                const float4 uB = *(const float4*)(gp + 4);
                const int m = 32 >> w;
                const float br = __shfl_xor(ar, m);
                const float bi = __shfl_xor(ai, m);
                const bool hi = (lane & m) != 0;
                const float cmr = hi ? uB.z : uA.x;
                const float cmi = hi ? uB.w : uA.y;
                const float cpr = hi ? uB.x : uA.z;
                const float cpi = hi ? uB.y : uA.w;
                const float nr = cmr * ar - cmi * ai + cpr * br - cpi * bi;
                const float ni = cmr * ai + cmi * ar + cpr * bi + cpi * br;
                ar = nr; ai = ni;
            }
            const int src = l ? src1 : src0;
            ar = __shfl(ar, src);
            ai = __shfl(ai, src);
        }
    }
    Mhi[((f * 2 + 0) * 64 + lane) * 64 + bas] = f2bf(ar);
    Mhi[((f * 2 + 1) * 64 + lane) * 64 + bas] = f2bf(ai);
}

// ---------------------------------------------------------------------------
// Main: R12 structure (2 tiles x 64 patches, waves <-> d-quarters, permlane
// reductions, packed double-buffered zbuf) with the f-loop FULLY UNROLLED and
// VGPR headroom (256,3) so the 16 B-fragments stay register-resident instead
// of being re-read from LDS every f iteration.
// ---------------------------------------------------------------------------
__global__ __launch_bounds__(256, 3) void qconv_main(
        const float* __restrict__ x,
        const unsigned short* __restrict__ Mhi,
        float* __restrict__ out) {
    __shared__ __align__(16) unsigned short psiH[2][4096];   // 16 KB
    __shared__ float zbuf[2][2][4][64][8];                   // 32 KB [fb][t][w][p][q8]

    const int tid  = threadIdx.x;
    const int lane = tid & 63;
    const int w    = tid >> 6;
    const int bid  = blockIdx.x;

    // ---- front-end: both tiles (tile t: batch b0 + 64t, same pos/i/j) ----
    {
        const int p = tid >> 2;          // patch 0..63
        const int q = tid & 3;           // channel / k-chunk
        const int n = bid * 64 + p;
        const int b0 = n / 961, pos = n - b0 * 961;
        const int i = pos / 31, j = pos - i * 31;
        const float* base0 = x + (((b0 * 4 + q) * 64) + i * 2) * 64 + j * 2;
        float v[2][16];
#pragma unroll
        for (int t = 0; t < 2; ++t) {
            const float* base = base0 + t * 64 * 4 * 64 * 64;
#pragma unroll
            for (int kh = 0; kh < 4; ++kh) {
                const float* r = base + kh * 64;
                *(f32x2*)&v[t][kh * 4]     = *(const f32x2*)r;
                *(f32x2*)&v[t][kh * 4 + 2] = *(const f32x2*)(r + 2);
            }
        }
#pragma unroll
        for (int t = 0; t < 2; ++t) {
            float ss = 0.f;
#pragma unroll
            for (int k = 0; k < 16; ++k) ss += v[t][k] * v[t][k];
            ss += __shfl_xor(ss, 1);
            ss += __shfl_xor(ss, 2);
            const float rn = rsqrtf(ss);
            unsigned hu[8];
#pragma unroll
            for (int k2 = 0; k2 < 8; ++k2) {
                __bf16 h0 = (__bf16)(v[t][2 * k2] * rn);
                __bf16 h1 = (__bf16)(v[t][2 * k2 + 1] * rn);
                hu[k2] = (unsigned)__builtin_bit_cast(unsigned short, h0)
                       | ((unsigned)__builtin_bit_cast(unsigned short, h1) << 16);
            }
            const int s0i = p * 64 + ((2 * q) ^ (p & 7)) * 8;
            const int s1i = p * 64 + ((2 * q + 1) ^ (p & 7)) * 8;
            *(uint4*)&psiH[t][s0i] = make_uint4(hu[0], hu[1], hu[2], hu[3]);
            *(uint4*)&psiH[t][s1i] = make_uint4(hu[4], hu[5], hu[6], hu[7]);
        }
    }

    // A-row base (verified mapping): reim lane bit4, d = w*16+(lane&15), k-half hi5*8
    const int hi5  = lane >> 5;
    const int arow = ((lane >> 4) & 1) * 4096 + (w * 16 + (lane & 15)) * 64 + hi5 * 8;

    // prefetch A for f=0 — hides under the barrier
    bf16x8 A[4];
#pragma unroll
    for (int ks = 0; ks < 4; ++ks) A[ks] = ldg8(Mhi + arow + ks * 16);

    __syncthreads();

    // ---- B-fragments for both tiles (register-resident) ----
    bf16x8 Bh[2][2][4];
    const int pc = lane & 31;
#pragma unroll
    for (int t = 0; t < 2; ++t) {
#pragma unroll
        for (int ct = 0; ct < 2; ++ct) {
            const int pp = ct * 32 + pc;
#pragma unroll
            for (int ks = 0; ks < 4; ++ks) {
                const int idx = pp * 64 + ((2 * ks + hi5) ^ (pp & 7)) * 8;
                Bh[t][ct][ks] = __builtin_bit_cast(bf16x8, *(const uint4*)&psiH[t][idx]);
            }
        }
    }

    // hoisted combine addressing (f-independent)
    const int ctile = tid >> 7;            // tile
    const int cp    = (tid >> 1) & 63;     // patch
    const int chalf = tid & 1;             // 0: q0-2, 1: q3-5
    const int cnn   = bid * 64 + cp;
    const int cbb   = cnn / 961;
    const int cpos  = cnn - cbb * 961;
    float* const obase = out + (((cbb + ctile * 64) * 24) + chalf * 3) * 961 + cpos;

#pragma unroll
    for (int f = 0; f < 4; ++f) {
        // ---- tile 0 chains ----
        f32x16 C0, C1;
#pragma unroll
        for (int r = 0; r < 16; ++r) { C0[r] = 0.f; C1[r] = 0.f; }
#pragma unroll
        for (int ks = 0; ks < 4; ++ks) {
            C0 = mfma32(A[ks], Bh[0][0][ks], C0);
            C1 = mfma32(A[ks], Bh[0][1][ks], C1);
        }

        // prefetch next f's A
        bf16x8 An[4];
        if (f < 3) {
#pragma unroll
            for (int ks = 0; ks < 4; ++ks)
                An[ks] = ldg8(Mhi + (f + 1) * 8192 + arow + ks * 16);
        }

#pragma unroll
        for (int t = 0; t < 2; ++t) {
            if (t == 1) {
#pragma unroll
                for (int r = 0; r < 16; ++r) { C0[r] = 0.f; C1[r] = 0.f; }
#pragma unroll
                for (int ks = 0; ks < 4; ++ks) {
                    C0 = mfma32(A[ks], Bh[1][0][ks], C0);
                    C1 = mfma32(A[ks], Bh[1][1][ks], C1);
                }
            }
#pragma unroll
            for (int ct = 0; ct < 2; ++ct) {
                const f32x16 Cv = ct ? C1 : C0;
                float P[8];
#pragma unroll
                for (int r = 0; r < 8; ++r) P[r] = Cv[r] * Cv[r] + Cv[r + 8] * Cv[r + 8];
                const float e0 = P[0] + P[1], o0 = P[0] - P[1];
                const float e1 = P[2] + P[3], o1 = P[2] - P[3];
                const float e2 = P[4] + P[5], o2 = P[4] - P[5];
                const float e3 = P[6] + P[7], o3 = P[6] - P[7];
                const float s01 = e0 + e1, s23 = e2 + e3;
                const float S = s01 + s23;
                const float Sr  = sum_xor32(S);
                const float Z2r = sum_xor32(s01 - s23);               // d bit3
                const float Z3r = sum_xor32(hi5 ? -S : S);            // d bit2
                const float Z4r = sum_xor32((e0 - e1) + (e2 - e3));   // d bit1
                const float Z5r = sum_xor32(o0 + o1 + o2 + o3);       // d bit0
                const int pp = ct * 32 + pc;
                float* zb = &zbuf[f & 1][t][w][pp][0];
                f32x2 d2;
                float d1;
                if (hi5 == 0) {
                    d2[0] = (w & 2) ? -Sr : Sr;    // q0: d bit5 = w>>1
                    d2[1] = (w & 1) ? -Sr : Sr;    // q1: d bit4 = w&1
                    d1 = Z2r;
                } else {
                    d2[0] = Z3r;
                    d2[1] = Z4r;
                    d1 = Z5r;
                }
                *(f32x2*)(zb + hi5 * 4) = d2;
                zb[hi5 * 4 + 2] = d1;
            }
        }
        __syncthreads();

        // ---- combine across waves + store (all 256 threads) ----
        {
            float a0 = 0.f, a1 = 0.f, a2 = 0.f;
#pragma unroll
            for (int ww = 0; ww < 4; ++ww) {
                const float* zb = &zbuf[f & 1][ctile][ww][cp][chalf * 4];
                const f32x2 v2 = *(const f32x2*)zb;
                a0 += v2[0]; a1 += v2[1]; a2 += zb[2];
            }
            float* o = obase + f * 6 * 961;
            o[0]       = a0;
            o[961]     = a1;
            o[2 * 961] = a2;
        }

        if (f < 3) {
#pragma unroll
            for (int ks = 0; ks < 4; ++ks) A[ks] = An[ks];
        }
    }
}

extern "C" void kernel_launch(void* const* d_in, const int* in_sizes, int n_in,
                              void* d_out, int out_size, void* d_ws, size_t ws_size,
                              hipStream_t stream) {
    const float* x   = (const float*)d_in[0];   // (128, 4, 64, 64)
    const float* wts = (const float*)d_in[1];   // (4, 2, 6, 3)
    float* out = (float*)d_out;                 // (128, 24, 31, 31)

    unsigned short* Mhi = (unsigned short*)d_ws;

    prep_M<<<64, 256, 0, stream>>>(wts, Mhi);

    // 123008 patches = 961 blocks x 2 tiles x 64 patches
    qconv_main<<<961, 256, 0, stream>>>(x, Mhi, out);
}

// Round 19
// 27.290 us; speedup vs baseline: 3.3803x; 1.0093x over previous
//
#include <hip/hip_runtime.h>

typedef float f32x2 __attribute__((ext_vector_type(2)));
typedef float f32x16 __attribute__((ext_vector_type(16)));
typedef __bf16 bf16x8 __attribute__((ext_vector_type(8)));

static __device__ __forceinline__ unsigned short f2bf(float v) {
    unsigned u = __builtin_bit_cast(unsigned, v);
    unsigned r = (u + 0x7FFFu + ((u >> 16) & 1u)) >> 16;
    return (unsigned short)r;
}
static __device__ __forceinline__ bf16x8 ldg8(const unsigned short* p) {
    uint4 u = *(const uint4*)p;
    return __builtin_bit_cast(bf16x8, u);
}
static __device__ __forceinline__ f32x16 mfma32(bf16x8 a, bf16x8 b, f32x16 c) {
    return __builtin_amdgcn_mfma_f32_32x32x16_bf16(a, b, c, 0, 0, 0);
}

// x + x[lane^32] on the VALU pipe (permlane32_swap), not the LDS pipe.
static __device__ __forceinline__ float sum_xor32(float x) {
#if __has_builtin(__builtin_amdgcn_permlane32_swap)
    unsigned u = __builtin_bit_cast(unsigned, x);
    auto r = __builtin_amdgcn_permlane32_swap(u, u, false, false);
    return __builtin_bit_cast(float, (unsigned)r[0]) +
           __builtin_bit_cast(float, (unsigned)r[1]);
#else
    return x + __shfl_xor(x, 32);
#endif
}

// ---------------------------------------------------------------------------
// prep_M: simulate the 64 basis states for each f -> M_f (64x64 complex),
// bf16, layout [f][re/im][d][k]. (verified R1-R18)
// ---------------------------------------------------------------------------
__global__ __launch_bounds__(256) void prep_M(const float* __restrict__ wts,
                                              unsigned short* __restrict__ Mhi) {
    __shared__ float gls[12][8];
    const int f = blockIdx.x >> 4;
    const int tid = threadIdx.x;
    if (tid < 12) {
        int l = tid / 6, w = tid % 6;
        const float* p = wts + ((f * 2 + l) * 6 + w) * 3;
        float phi = p[0], theta = p[1], omega = p[2];
        float c, s; sincosf(0.5f * theta, &s, &c);
        float sapo, capo, samo, camo;
        sincosf(0.5f * (phi + omega), &sapo, &capo);
        sincosf(0.5f * (phi - omega), &samo, &camo);
        float* o = gls[tid];
        o[0] =  capo * c;  o[1] = -sapo * c;
        o[2] = -camo * s;  o[3] = -samo * s;
        o[4] =  camo * s;  o[5] = -samo * s;
        o[6] =  capo * c;  o[7] =  sapo * c;
    }
    __syncthreads();

    const int lane = tid & 63;
    const int wid  = tid >> 6;
    const int bas  = (blockIdx.x & 15) * 4 + wid;

    int src0 = lane, src1 = lane;
#pragma unroll
    for (int w = 5; w >= 0; --w) { int tq = (w + 1) % 6; src0 ^= ((src0 >> (5 - w)) & 1) << (5 - tq); }
#pragma unroll
    for (int w = 5; w >= 0; --w) { int tq = (w + 2) % 6; src1 ^= ((src1 >> (5 - w)) & 1) << (5 - tq); }

    float ar = (lane == bas) ? 1.0f : 0.0f, ai = 0.0f;
#pragma unroll
    for (int rep = 0; rep < 2; ++rep) {
#pragma unroll
        for (int l = 0; l < 2; ++l) {
#pragma unroll
            for (int w = 0; w < 6; ++w) {
                const float* gp = gls[l * 6 + w];
                const float4 uA = *(const float4*)gp;
                const float4 uB = *(const float4*)(gp + 4);
                const int m = 32 >> w;
                const float br = __shfl_xor(ar, m);
                const float bi = __shfl_xor(ai, m);
                const bool hi = (lane & m) != 0;
                const float cmr = hi ? uB.z : uA.x;
                const float cmi = hi ? uB.w : uA.y;
                const float cpr = hi ? uB.x : uA.z;
                const float cpi = hi ? uB.y : uA.w;
                const float nr = cmr * ar - cmi * ai + cpr * br - cpi * bi;
                const float ni = cmr * ai + cmi * ar + cpr * bi + cpi * br;
                ar = nr; ai = ni;
            }
            const int src = l ? src1 : src0;
            ar = __shfl(ar, src);
            ai = __shfl(ai, src);
        }
    }
    Mhi[((f * 2 + 0) * 64 + lane) * 64 + bas] = f2bf(ar);
    Mhi[((f * 2 + 1) * 64 + lane) * 64 + bas] = f2bf(ai);
}

// ---------------------------------------------------------------------------
// Main: R18 (register-resident B-frags, fully unrolled f-loop) with the
// cross-wave combine DEFERRED one iteration: combine(f-1) executes before
// barrier(f), filling the MFMA/epilogue shadow instead of the barrier tail.
// ---------------------------------------------------------------------------
__global__ __launch_bounds__(256, 3) void qconv_main(
        const float* __restrict__ x,
        const unsigned short* __restrict__ Mhi,
        float* __restrict__ out) {
    __shared__ __align__(16) unsigned short psiH[2][4096];   // 16 KB
    __shared__ float zbuf[2][2][4][64][8];                   // 32 KB [fb][t][w][p][q8]

    const int tid  = threadIdx.x;
    const int lane = tid & 63;
    const int w    = tid >> 6;
    const int bid  = blockIdx.x;

    // ---- front-end: both tiles (tile t: batch b0 + 64t, same pos/i/j) ----
    {
        const int p = tid >> 2;          // patch 0..63
        const int q = tid & 3;           // channel / k-chunk
        const int n = bid * 64 + p;
        const int b0 = n / 961, pos = n - b0 * 961;
        const int i = pos / 31, j = pos - i * 31;
        const float* base0 = x + (((b0 * 4 + q) * 64) + i * 2) * 64 + j * 2;
        float v[2][16];
#pragma unroll
        for (int t = 0; t < 2; ++t) {
            const float* base = base0 + t * 64 * 4 * 64 * 64;
#pragma unroll
            for (int kh = 0; kh < 4; ++kh) {
                const float* r = base + kh * 64;
                *(f32x2*)&v[t][kh * 4]     = *(const f32x2*)r;
                *(f32x2*)&v[t][kh * 4 + 2] = *(const f32x2*)(r + 2);
            }
        }
#pragma unroll
        for (int t = 0; t < 2; ++t) {
            float ss = 0.f;
#pragma unroll
            for (int k = 0; k < 16; ++k) ss += v[t][k] * v[t][k];
            ss += __shfl_xor(ss, 1);
            ss += __shfl_xor(ss, 2);
            const float rn = rsqrtf(ss);
            unsigned hu[8];
#pragma unroll
            for (int k2 = 0; k2 < 8; ++k2) {
                __bf16 h0 = (__bf16)(v[t][2 * k2] * rn);
                __bf16 h1 = (__bf16)(v[t][2 * k2 + 1] * rn);
                hu[k2] = (unsigned)__builtin_bit_cast(unsigned short, h0)
                       | ((unsigned)__builtin_bit_cast(unsigned short, h1) << 16);
            }
            const int s0i = p * 64 + ((2 * q) ^ (p & 7)) * 8;
            const int s1i = p * 64 + ((2 * q + 1) ^ (p & 7)) * 8;
            *(uint4*)&psiH[t][s0i] = make_uint4(hu[0], hu[1], hu[2], hu[3]);
            *(uint4*)&psiH[t][s1i] = make_uint4(hu[4], hu[5], hu[6], hu[7]);
        }
    }

    // A-row base (verified mapping): reim lane bit4, d = w*16+(lane&15), k-half hi5*8
    const int hi5  = lane >> 5;
    const int arow = ((lane >> 4) & 1) * 4096 + (w * 16 + (lane & 15)) * 64 + hi5 * 8;

    // prefetch A for f=0 — hides under the barrier
    bf16x8 A[4];
#pragma unroll
    for (int ks = 0; ks < 4; ++ks) A[ks] = ldg8(Mhi + arow + ks * 16);

    __syncthreads();

    // ---- B-fragments for both tiles (register-resident) ----
    bf16x8 Bh[2][2][4];
    const int pc = lane & 31;
#pragma unroll
    for (int t = 0; t < 2; ++t) {
#pragma unroll
        for (int ct = 0; ct < 2; ++ct) {
            const int pp = ct * 32 + pc;
#pragma unroll
            for (int ks = 0; ks < 4; ++ks) {
                const int idx = pp * 64 + ((2 * ks + hi5) ^ (pp & 7)) * 8;
                Bh[t][ct][ks] = __builtin_bit_cast(bf16x8, *(const uint4*)&psiH[t][idx]);
            }
        }
    }

    // hoisted combine addressing (f-independent)
    const int ctile = tid >> 7;            // tile
    const int cp    = (tid >> 1) & 63;     // patch
    const int chalf = tid & 1;             // 0: q0-2, 1: q3-5
    const int cnn   = bid * 64 + cp;
    const int cbb   = cnn / 961;
    const int cpos  = cnn - cbb * 961;
    float* const obase = out + (((cbb + ctile * 64) * 24) + chalf * 3) * 961 + cpos;

#pragma unroll
    for (int f = 0; f < 4; ++f) {
        // ---- tile 0 chains (register-only, independent of barrier state) ----
        f32x16 C0, C1;
#pragma unroll
        for (int r = 0; r < 16; ++r) { C0[r] = 0.f; C1[r] = 0.f; }
#pragma unroll
        for (int ks = 0; ks < 4; ++ks) {
            C0 = mfma32(A[ks], Bh[0][0][ks], C0);
            C1 = mfma32(A[ks], Bh[0][1][ks], C1);
        }

        // prefetch next f's A
        bf16x8 An[4];
        if (f < 3) {
#pragma unroll
            for (int ks = 0; ks < 4; ++ks)
                An[ks] = ldg8(Mhi + (f + 1) * 8192 + arow + ks * 16);
        }

        // ---- deferred combine of f-1 (reads zbuf[(f-1)&1], published by
        //      barrier(f-1)) — fills the MFMA/epilogue shadow ----
        if (f > 0) {
            float a0 = 0.f, a1 = 0.f, a2 = 0.f;
#pragma unroll
            for (int ww = 0; ww < 4; ++ww) {
                const float* zb = &zbuf[(f - 1) & 1][ctile][ww][cp][chalf * 4];
                const f32x2 v2 = *(const f32x2*)zb;
                a0 += v2[0]; a1 += v2[1]; a2 += zb[2];
            }
            float* o = obase + (f - 1) * 6 * 961;
            o[0]       = a0;
            o[961]     = a1;
            o[2 * 961] = a2;
        }

#pragma unroll
        for (int t = 0; t < 2; ++t) {
            if (t == 1) {
#pragma unroll
                for (int r = 0; r < 16; ++r) { C0[r] = 0.f; C1[r] = 0.f; }
#pragma unroll
                for (int ks = 0; ks < 4; ++ks) {
                    C0 = mfma32(A[ks], Bh[1][0][ks], C0);
                    C1 = mfma32(A[ks], Bh[1][1][ks], C1);
                }
            }
#pragma unroll
            for (int ct = 0; ct < 2; ++ct) {
                const f32x16 Cv = ct ? C1 : C0;
                float P[8];
#pragma unroll
                for (int r = 0; r < 8; ++r) P[r] = Cv[r] * Cv[r] + Cv[r + 8] * Cv[r + 8];
                const float e0 = P[0] + P[1], o0 = P[0] - P[1];
                const float e1 = P[2] + P[3], o1 = P[2] - P[3];
                const float e2 = P[4] + P[5], o2 = P[4] - P[5];
                const float e3 = P[6] + P[7], o3 = P[6] - P[7];
                const float s01 = e0 + e1, s23 = e2 + e3;
                const float S = s01 + s23;
                const float Sr  = sum_xor32(S);
                const float Z2r = sum_xor32(s01 - s23);               // d bit3
                const float Z3r = sum_xor32(hi5 ? -S : S);            // d bit2
                const float Z4r = sum_xor32((e0 - e1) + (e2 - e3));   // d bit1
                const float Z5r = sum_xor32(o0 + o1 + o2 + o3);       // d bit0
                const int pp = ct * 32 + pc;
                float* zb = &zbuf[f & 1][t][w][pp][0];
                f32x2 d2;
                float d1;
                if (hi5 == 0) {
                    d2[0] = (w & 2) ? -Sr : Sr;    // q0: d bit5 = w>>1
                    d2[1] = (w & 1) ? -Sr : Sr;    // q1: d bit4 = w&1
                    d1 = Z2r;
                } else {
                    d2[0] = Z3r;
                    d2[1] = Z4r;
                    d1 = Z5r;
                }
                *(f32x2*)(zb + hi5 * 4) = d2;
                zb[hi5 * 4 + 2] = d1;
            }
        }
        __syncthreads();   // publish zbuf[f&1]

        if (f < 3) {
#pragma unroll
            for (int ks = 0; ks < 4; ++ks) A[ks] = An[ks];
        }
    }

    // ---- final combine (f=3), published by the last barrier ----
    {
        float a0 = 0.f, a1 = 0.f, a2 = 0.f;
#pragma unroll
        for (int ww = 0; ww < 4; ++ww) {
            const float* zb = &zbuf[3 & 1][ctile][ww][cp][chalf * 4];
            const f32x2 v2 = *(const f32x2*)zb;
            a0 += v2[0]; a1 += v2[1]; a2 += zb[2];
        }
        float* o = obase + 3 * 6 * 961;
        o[0]       = a0;
        o[961]     = a1;
        o[2 * 961] = a2;
    }
}

extern "C" void kernel_launch(void* const* d_in, const int* in_sizes, int n_in,
                              void* d_out, int out_size, void* d_ws, size_t ws_size,
                              hipStream_t stream) {
    const float* x   = (const float*)d_in[0];   // (128, 4, 64, 64)
    const float* wts = (const float*)d_in[1];   // (4, 2, 6, 3)
    float* out = (float*)d_out;                 // (128, 24, 31, 31)

    unsigned short* Mhi = (unsigned short*)d_ws;

    prep_M<<<64, 256, 0, stream>>>(wts, Mhi);

    // 123008 patches = 961 blocks x 2 tiles x 64 patches
    qconv_main<<<961, 256, 0, stream>>>(x, Mhi, out);
}